// Round 4
// baseline (434.355 us; speedup 1.0000x reference)
//
#include <hip/hip_runtime.h>
#include <math.h>

#define N_NODES 50000
#define N_EDGES 600000
#define DIM 128
#define HEADS 8
#define NBLK 196  // (N_NODES+255)/256
#define DBINS 64

typedef short v8s __attribute__((ext_vector_type(8)));
typedef float v16f __attribute__((ext_vector_type(16)));

__device__ __forceinline__ short f2bf(float f) {
    unsigned int u = __float_as_uint(f);
    unsigned int r = (u + 0x7fffu + ((u >> 16) & 1u)) >> 16;  // RNE
    return (short)r;
}

__device__ __forceinline__ void bf8_to_f(v8s s, float* f) {
    union { v8s s; unsigned int u[4]; } cv;
    cv.s = s;
#pragma unroll
    for (int j = 0; j < 4; j++) {
        f[2 * j + 0] = __uint_as_float(cv.u[j] << 16);
        f[2 * j + 1] = __uint_as_float(cv.u[j] & 0xFFFF0000u);
    }
}

// ---------------- CSR build ----------------
__global__ __launch_bounds__(256) void init_counts(int* __restrict__ counts,
                                                   int* __restrict__ bins) {
    int i = blockIdx.x * 256 + threadIdx.x;
    if (i < N_NODES) counts[i] = 0;
    if (blockIdx.x == 0 && threadIdx.x < DBINS) bins[threadIdx.x] = 0;
}

__global__ __launch_bounds__(256) void hist_kernel(const int* __restrict__ rowi,
                                                   int* __restrict__ counts) {
    int e = blockIdx.x * 256 + threadIdx.x;
    if (e >= N_EDGES) return;
    atomicAdd(counts + rowi[e], 1);
}

__global__ __launch_bounds__(256) void reduce_partials(const int* __restrict__ counts,
                                                       int* __restrict__ partials) {
    int idx = blockIdx.x * 256 + threadIdx.x;
    int v = (idx < N_NODES) ? counts[idx] : 0;
#pragma unroll
    for (int off = 32; off > 0; off >>= 1) v += __shfl_down(v, off);
    __shared__ int ws4[4];
    if ((threadIdx.x & 63) == 0) ws4[threadIdx.x >> 6] = v;
    __syncthreads();
    if (threadIdx.x == 0) partials[blockIdx.x] = ws4[0] + ws4[1] + ws4[2] + ws4[3];
}

__global__ __launch_bounds__(256) void scan_partials(const int* __restrict__ partials,
                                                     int* __restrict__ offsets) {
    __shared__ int sh[256];
    int t = threadIdx.x;
    int v = (t < NBLK) ? partials[t] : 0;
    sh[t] = v;
    __syncthreads();
    for (int off = 1; off < 256; off <<= 1) {
        int a = sh[t];
        int b = (t >= off) ? sh[t - off] : 0;
        __syncthreads();
        sh[t] = a + b;
        __syncthreads();
    }
    if (t < NBLK) offsets[t] = sh[t] - v;  // exclusive
}

__global__ __launch_bounds__(256) void block_scan(const int* __restrict__ counts,
                                                  const int* __restrict__ offsets,
                                                  int* __restrict__ start,
                                                  int* __restrict__ writeptr) {
    __shared__ int sh[256];
    int t = threadIdx.x;
    int idx = blockIdx.x * 256 + t;
    int v = (idx < N_NODES) ? counts[idx] : 0;
    sh[t] = v;
    __syncthreads();
    for (int off = 1; off < 256; off <<= 1) {
        int a = sh[t];
        int b = (t >= off) ? sh[t - off] : 0;
        __syncthreads();
        sh[t] = a + b;
        __syncthreads();
    }
    if (idx < N_NODES) {
        int s = offsets[blockIdx.x] + sh[t] - v;
        start[idx] = s;
        writeptr[idx] = s;
    }
}

__global__ __launch_bounds__(256) void scatter_kernel(const int* __restrict__ rowi,
                                                      const int* __restrict__ coli,
                                                      const float* __restrict__ eattr,
                                                      int* __restrict__ writeptr,
                                                      int2* __restrict__ ep) {
    int e = blockIdx.x * 256 + threadIdx.x;
    if (e >= N_EDGES) return;
    int r = rowi[e];
    int pos = atomicAdd(writeptr + r, 1);
    ep[pos] = make_int2(coli[e], __float_as_int(eattr[e]));
}

// ---------------- degree-balanced node permutation (counting sort by degree) ----------------
__global__ __launch_bounds__(256) void deg_hist(const int* __restrict__ counts,
                                                int* __restrict__ bins) {
    __shared__ int lb[DBINS];
    if (threadIdx.x < DBINS) lb[threadIdx.x] = 0;
    __syncthreads();
    int i = blockIdx.x * 256 + threadIdx.x;
    if (i < N_NODES) atomicAdd(lb + min(counts[i], DBINS - 1), 1);
    __syncthreads();
    if (threadIdx.x < DBINS) {
        int v = lb[threadIdx.x];
        if (v) atomicAdd(bins + threadIdx.x, v);
    }
}

__global__ __launch_bounds__(64) void deg_scan(const int* __restrict__ bins,
                                               int* __restrict__ bptr) {
    int t = threadIdx.x;
    int v = bins[t];
    int s = v;
#pragma unroll
    for (int off = 1; off < 64; off <<= 1) {
        int u = __shfl_up(s, off);
        if (t >= off) s += u;
    }
    bptr[t] = s - v;  // exclusive
}

__global__ __launch_bounds__(256) void deg_scatter(const int* __restrict__ counts,
                                                   int* __restrict__ bptr,
                                                   int* __restrict__ perm) {
    int i = blockIdx.x * 256 + threadIdx.x;
    if (i >= N_NODES) return;
    int b = min(counts[i], DBINS - 1);
    int pos = atomicAdd(bptr + b, 1);
    perm[pos] = i;
}

// ---------------- conversions ----------------
__global__ __launch_bounds__(256) void convert_x(const float* __restrict__ x,
                                                 short* __restrict__ xb) {
    int base = (blockIdx.x * 256 + threadIdx.x) * 4;
    if (base >= N_NODES * DIM) return;
    float4 v = *(const float4*)(x + base);
    *(short4*)(xb + base) = make_short4(f2bf(v.x), f2bf(v.y), f2bf(v.z), f2bf(v.w));
}

__global__ __launch_bounds__(256) void convert_w(const float* __restrict__ Wq,
                                                 const float* __restrict__ Wk,
                                                 const float* __restrict__ Wv,
                                                 const float* __restrict__ Wo,
                                                 short* __restrict__ out) {
    int base = (blockIdx.x * 256 + threadIdx.x) * 4;
    if (base >= 4 * DIM * DIM) return;
    int seg = base >> 14;
    const float* src = (seg == 0) ? Wq : (seg == 1) ? Wk : (seg == 2) ? Wv : Wo;
    int off = base & (DIM * DIM - 1);
    float4 v = *(const float4*)(src + off);
    *(short4*)(out + base) = make_short4(f2bf(v.x), f2bf(v.y), f2bf(v.z), f2bf(v.w));
}

// ---------------- bf16 MFMA GEMM core ----------------
__device__ __forceinline__ void store_out(float* C, size_t idx, float v) { C[idx] = v; }
__device__ __forceinline__ void store_out(short* C, size_t idx, float v) { C[idx] = f2bf(v); }

template <typename OutT>
__device__ __forceinline__ void gemm_core(const short* __restrict__ Ab,
                                          const short* __restrict__ Wb,
                                          const float* __restrict__ bias,
                                          OutT* __restrict__ C, int M) {
    int wave = threadIdx.x >> 6;
    int lane = threadIdx.x & 63;
    int col0 = wave * 32;
    int m32 = lane & 31;
    int quad = lane >> 5;

    v8s zeroS;
#pragma unroll
    for (int j = 0; j < 8; j++) zeroS[j] = 0;

    v8s bf[8];
    const short* wp = Wb + col0 + m32;
#pragma unroll
    for (int kt = 0; kt < 8; kt++) {
        v8s f;
#pragma unroll
        for (int j = 0; j < 8; j++) f[j] = wp[(kt * 16 + quad * 8 + j) * 128];
        bf[kt] = f;
    }
    float bias_v = bias[col0 + m32];

    const int NT = (M + 31) / 32;
    for (int rt = blockIdx.x; rt < NT; rt += gridDim.x) {
        int row0 = rt * 32;
        int grow = row0 + m32;
        bool valid = grow < M;
        const v8s* ap = (const v8s*)(Ab + (size_t)grow * 128 + quad * 8);
        v16f acc;
#pragma unroll
        for (int r = 0; r < 16; r++) acc[r] = 0.0f;
#pragma unroll
        for (int kt = 0; kt < 8; kt++) {
            v8s af = zeroS;
            if (valid) af = ap[kt * 2];
            acc = __builtin_amdgcn_mfma_f32_32x32x16_bf16(af, bf[kt], acc, 0, 0, 0);
        }
#pragma unroll
        for (int r = 0; r < 16; r++) {
            int row = (r & 3) + 8 * (r >> 2) + 4 * quad;
            int gr = row0 + row;
            if (gr < M) store_out(C, (size_t)gr * 128 + col0 + m32, acc[r] + bias_v);
        }
    }
}

__global__ __launch_bounds__(256) void gemm_qkv(const short* __restrict__ xb,
                                                const short* __restrict__ Wb_all,
                                                const float* __restrict__ bq,
                                                const float* __restrict__ bk,
                                                const float* __restrict__ bv,
                                                float* __restrict__ Qf,
                                                short* __restrict__ Kb,
                                                short* __restrict__ Vb) {
    int y = blockIdx.y;
    if (y == 0)      gemm_core(xb, Wb_all, bq, Qf, N_NODES);
    else if (y == 1) gemm_core(xb, Wb_all + DIM * DIM, bk, Kb, N_NODES);
    else             gemm_core(xb, Wb_all + 2 * DIM * DIM, bv, Vb, N_NODES);
}

__global__ __launch_bounds__(256) void gemm_out(const short* __restrict__ Ab,
                                                const short* __restrict__ Wb_all,
                                                const float* __restrict__ bo,
                                                float* __restrict__ C) {
    gemm_core(Ab, Wb_all + 3 * DIM * DIM, bo, C, N_NODES);
}

// ---------------- fused attention: bf16 gather + dual-stream online softmax ----------------
__global__ __launch_bounds__(256) void fused_attn(const float* __restrict__ Q,
                                                  const short* __restrict__ Kb,
                                                  const short* __restrict__ Vb,
                                                  const int* __restrict__ start,
                                                  const int* __restrict__ counts,
                                                  const int* __restrict__ perm,
                                                  const int2* __restrict__ ep,
                                                  short* __restrict__ Aout) {
    int t = blockIdx.x * 256 + threadIdx.x;
    int idx = t >> 3;
    int h = t & 7;
    if (idx >= N_NODES) return;
    int n = perm[idx];

    float qf[16];
#pragma unroll
    for (int j = 0; j < 4; j++) {
        float4 t4 = *(const float4*)(Q + (size_t)n * 128 + h * 16 + j * 4);
        qf[4 * j + 0] = t4.x; qf[4 * j + 1] = t4.y;
        qf[4 * j + 2] = t4.z; qf[4 * j + 3] = t4.w;
    }

    int s0 = start[n];
    int e1 = s0 + counts[n];

    float m0 = -INFINITY, l0 = 0.0f, m1 = -INFINITY, l1 = 0.0f;
    float accA[16], accB[16];
#pragma unroll
    for (int j = 0; j < 16; j++) { accA[j] = 0.0f; accB[j] = 0.0f; }

    auto step = [&](int i, float& m, float& l, float* acc) {
        int2 p = ep[i];
        int c = p.x;
        float ea = __int_as_float(p.y);
        const v8s* kp = (const v8s*)(Kb + (size_t)c * 128 + h * 16);
        v8s kr0 = kp[0], kr1 = kp[1];
        const v8s* vp = (const v8s*)(Vb + (size_t)c * 128 + h * 16);
        v8s vr0 = vp[0], vr1 = vp[1];
        float kf[16];
        bf8_to_f(kr0, kf); bf8_to_f(kr1, kf + 8);
        float dot = 0.0f;
#pragma unroll
        for (int j = 0; j < 16; j++) dot += qf[j] * kf[j];
        float s = dot * 0.25f + ea;
        float em = s;
        em = fmaxf(em, __shfl_xor(em, 1));
        em = fmaxf(em, __shfl_xor(em, 2));
        em = fmaxf(em, __shfl_xor(em, 4));
        float nm = fmaxf(m, em);
        float scale = __expf(m - nm);
        float ex = __expf(s - nm);
        l = l * scale + ex;
        float vf[16];
        bf8_to_f(vr0, vf); bf8_to_f(vr1, vf + 8);
#pragma unroll
        for (int j = 0; j < 16; j++) acc[j] = acc[j] * scale + ex * vf[j];
        m = nm;
    };

    int i = s0;
    for (; i + 1 < e1; i += 2) {
        step(i, m0, l0, accA);
        step(i + 1, m1, l1, accB);
    }
    if (i < e1) step(i, m0, l0, accA);

    // merge the two streams
    float mm = fmaxf(m0, m1);
    float w0 = (l0 > 0.0f) ? __expf(m0 - mm) : 0.0f;
    float w1 = (l1 > 0.0f) ? __expf(m1 - mm) : 0.0f;
    float l = l0 * w0 + l1 * w1;
    float inv = 1.0f / (l + 1e-8f);

    unsigned short tmp[16];
#pragma unroll
    for (int j = 0; j < 16; j++) tmp[j] = (unsigned short)f2bf((accA[j] * w0 + accB[j] * w1) * inv);
    short* o = Aout + (size_t)n * 128 + h * 16;
    *(v8s*)(o) = *(v8s*)tmp;
    *(v8s*)(o + 8) = *(v8s*)(tmp + 8);
}

extern "C" void kernel_launch(void* const* d_in, const int* in_sizes, int n_in,
                              void* d_out, int out_size, void* d_ws, size_t ws_size,
                              hipStream_t stream) {
    const float* x = (const float*)d_in[0];
    const int* ei = (const int*)d_in[1];
    const float* eattr = (const float*)d_in[2];
    const float* Wq = (const float*)d_in[3];
    const float* bq = (const float*)d_in[4];
    const float* Wk = (const float*)d_in[5];
    const float* bk = (const float*)d_in[6];
    const float* Wv = (const float*)d_in[7];
    const float* bv = (const float*)d_in[8];
    const float* Wo = (const float*)d_in[9];
    const float* bo = (const float*)d_in[10];
    float* out = (float*)d_out;

    const int* rowi = ei;
    const int* coli = ei + N_EDGES;

    // workspace carve (all segments 8B-aligned)
    float* Qf = (float*)d_ws;                          // N*128 f32
    short* Kb = (short*)(Qf + (size_t)N_NODES * DIM);  // N*128 bf16
    short* Vb = Kb + (size_t)N_NODES * DIM;
    short* xb = Vb + (size_t)N_NODES * DIM;
    short* Aout = xb + (size_t)N_NODES * DIM;
    short* Wb = Aout + (size_t)N_NODES * DIM;          // 4*128*128
    int* counts = (int*)(Wb + 4 * DIM * DIM);
    int* start = counts + N_NODES;
    int* writeptr = start + N_NODES;
    int* partials = writeptr + N_NODES;  // 256
    int* offsets = partials + 256;       // 256
    int* bins = offsets + 256;           // 64
    int* bptr = bins + 64;               // 64
    int* perm = bptr + 64;               // N
    int2* ep = (int2*)(perm + N_NODES);  // E

    int eblocks = (N_EDGES + 255) / 256;

    // CSR build + degree-balanced permutation
    init_counts<<<NBLK, 256, 0, stream>>>(counts, bins);
    hist_kernel<<<eblocks, 256, 0, stream>>>(rowi, counts);
    reduce_partials<<<NBLK, 256, 0, stream>>>(counts, partials);
    scan_partials<<<1, 256, 0, stream>>>(partials, offsets);
    block_scan<<<NBLK, 256, 0, stream>>>(counts, offsets, start, writeptr);
    scatter_kernel<<<eblocks, 256, 0, stream>>>(rowi, coli, eattr, writeptr, ep);
    deg_hist<<<NBLK, 256, 0, stream>>>(counts, bins);
    deg_scan<<<1, 64, 0, stream>>>(bins, bptr);
    deg_scatter<<<NBLK, 256, 0, stream>>>(counts, bptr, perm);

    // conversions
    convert_x<<<(N_NODES * DIM / 4 + 255) / 256, 256, 0, stream>>>(x, xb);
    convert_w<<<(4 * DIM * DIM / 4 + 255) / 256, 256, 0, stream>>>(Wq, Wk, Wv, Wo, Wb);

    // Q (f32) / K,V (bf16) projections
    gemm_qkv<<<dim3(392, 3), 256, 0, stream>>>(xb, Wb, bq, bk, bv, Qf, Kb, Vb);

    // fused gather-attention
    int ablocks = (N_NODES * HEADS + 255) / 256;
    fused_attn<<<ablocks, 256, 0, stream>>>(Qf, Kb, Vb, start, counts, perm, ep, Aout);

    // output projection
    gemm_out<<<392, 256, 0, stream>>>(Aout, Wb, bo, out);
}

// Round 6
// 265.824 us; speedup vs baseline: 1.6340x; 1.6340x over previous
//
#include <hip/hip_runtime.h>
#include <math.h>

#define N_NODES 50000
#define N_EDGES 600000
#define DIM 128
#define HEADS 8
#define NBLK 196
#define DBINS 64

typedef _Float16 v8h __attribute__((ext_vector_type(8)));
typedef _Float16 v2h __attribute__((ext_vector_type(2)));
typedef float v16f __attribute__((ext_vector_type(16)));

union v8h_u {
    v8h v;
    v2h p[4];
    _Float16 e[8];
};

__device__ __forceinline__ float dot2(v2h a, v2h b, float c) {
#if __has_builtin(__builtin_amdgcn_fdot2)
    return __builtin_amdgcn_fdot2(a, b, c, false);
#else
    return c + (float)a[0] * (float)b[0] + (float)a[1] * (float)b[1];
#endif
}

// ---------------- fused prep: zero counts/bins + convert x,W to f16 ----------------
__global__ __launch_bounds__(256) void prep_kernel(const float* __restrict__ x,
                                                   const float* __restrict__ Wq,
                                                   const float* __restrict__ Wk,
                                                   const float* __restrict__ Wv,
                                                   const float* __restrict__ Wo,
                                                   _Float16* __restrict__ xh,
                                                   _Float16* __restrict__ Wh,
                                                   int* __restrict__ counts,
                                                   int* __restrict__ bins) {
    int i = blockIdx.x * 256 + threadIdx.x;
    if (i < N_NODES) counts[i] = 0;
    if (i < DBINS) bins[i] = 0;
    int base = i * 4;
    if (base < N_NODES * DIM) {
        float4 v = *(const float4*)(x + base);
        _Float16 o[4] = {(_Float16)v.x, (_Float16)v.y, (_Float16)v.z, (_Float16)v.w};
        *(short4*)(xh + base) = *(short4*)o;
    }
    if (base < 4 * DIM * DIM) {
        int seg = base >> 14;
        const float* src = (seg == 0) ? Wq : (seg == 1) ? Wk : (seg == 2) ? Wv : Wo;
        int off = base & (DIM * DIM - 1);
        float4 v = *(const float4*)(src + off);
        _Float16 o[4] = {(_Float16)v.x, (_Float16)v.y, (_Float16)v.z, (_Float16)v.w};
        *(short4*)(Wh + base) = *(short4*)o;
    }
}

// ---------------- CSR build ----------------
__global__ __launch_bounds__(256) void hist_kernel(const int* __restrict__ rowi,
                                                   int* __restrict__ counts) {
    int e = blockIdx.x * 256 + threadIdx.x;
    if (e >= N_EDGES) return;
    atomicAdd(counts + rowi[e], 1);
}

__global__ __launch_bounds__(256) void reduce_partials(const int* __restrict__ counts,
                                                       int* __restrict__ partials) {
    int idx = blockIdx.x * 256 + threadIdx.x;
    int v = (idx < N_NODES) ? counts[idx] : 0;
#pragma unroll
    for (int off = 32; off > 0; off >>= 1) v += __shfl_down(v, off);
    __shared__ int ws4[4];
    if ((threadIdx.x & 63) == 0) ws4[threadIdx.x >> 6] = v;
    __syncthreads();
    if (threadIdx.x == 0) partials[blockIdx.x] = ws4[0] + ws4[1] + ws4[2] + ws4[3];
}

__global__ __launch_bounds__(256) void scan_partials(const int* __restrict__ partials,
                                                     int* __restrict__ offsets) {
    __shared__ int sh[256];
    int t = threadIdx.x;
    int v = (t < NBLK) ? partials[t] : 0;
    sh[t] = v;
    __syncthreads();
    for (int off = 1; off < 256; off <<= 1) {
        int a = sh[t];
        int b = (t >= off) ? sh[t - off] : 0;
        __syncthreads();
        sh[t] = a + b;
        __syncthreads();
    }
    if (t < NBLK) offsets[t] = sh[t] - v;  // exclusive
}

// block-level scan for CSR starts + fused degree histogram
__global__ __launch_bounds__(256) void block_scan(const int* __restrict__ counts,
                                                  const int* __restrict__ offsets,
                                                  int* __restrict__ start,
                                                  int* __restrict__ writeptr,
                                                  int* __restrict__ bins) {
    __shared__ int sh[256];
    __shared__ int lb[DBINS];
    int t = threadIdx.x;
    int idx = blockIdx.x * 256 + t;
    int v = (idx < N_NODES) ? counts[idx] : 0;
    if (t < DBINS) lb[t] = 0;
    sh[t] = v;
    __syncthreads();
    for (int off = 1; off < 256; off <<= 1) {
        int a = sh[t];
        int b = (t >= off) ? sh[t - off] : 0;
        __syncthreads();
        sh[t] = a + b;
        __syncthreads();
    }
    if (idx < N_NODES) {
        int s = offsets[blockIdx.x] + sh[t] - v;
        start[idx] = s;
        writeptr[idx] = s;
        atomicAdd(lb + min(v, DBINS - 1), 1);
    }
    __syncthreads();
    if (t < DBINS) {
        int c = lb[t];
        if (c) atomicAdd(bins + t, c);
    }
}

__global__ __launch_bounds__(256) void scatter_kernel(const int* __restrict__ rowi,
                                                      const int* __restrict__ coli,
                                                      const float* __restrict__ eattr,
                                                      int* __restrict__ writeptr,
                                                      int2* __restrict__ ep) {
    int e = blockIdx.x * 256 + threadIdx.x;
    if (e >= N_EDGES) return;
    int r = rowi[e];
    int pos = atomicAdd(writeptr + r, 1);
    ep[pos] = make_int2(coli[e], __float_as_int(eattr[e]));
}

__global__ __launch_bounds__(64) void deg_scan(const int* __restrict__ bins,
                                               int* __restrict__ bptr) {
    int t = threadIdx.x;
    int v = bins[t];
    int s = v;
#pragma unroll
    for (int off = 1; off < 64; off <<= 1) {
        int u = __shfl_up(s, off);
        if (t >= off) s += u;
    }
    bptr[t] = s - v;  // exclusive
}

// block-aggregated counting-sort scatter (1 global atomic per block,bin)
__global__ __launch_bounds__(256) void deg_scatter(const int* __restrict__ counts,
                                                   int* __restrict__ bptr,
                                                   int* __restrict__ perm) {
    __shared__ int lhist[DBINS];
    __shared__ int lbase[DBINS];
    if (threadIdx.x < DBINS) lhist[threadIdx.x] = 0;
    __syncthreads();
    int i = blockIdx.x * 256 + threadIdx.x;
    int b = -1, r = 0;
    if (i < N_NODES) {
        b = min(counts[i], DBINS - 1);
        r = atomicAdd(lhist + b, 1);
    }
    __syncthreads();
    if (threadIdx.x < DBINS) {
        int c = lhist[threadIdx.x];
        lbase[threadIdx.x] = c ? atomicAdd(bptr + threadIdx.x, c) : 0;
    }
    __syncthreads();
    if (b >= 0) perm[lbase[b] + r] = i;
}

// ---------------- f16 MFMA GEMM core ----------------
__device__ __forceinline__ void store_out(float* C, size_t idx, float v) { C[idx] = v; }
__device__ __forceinline__ void store_out(_Float16* C, size_t idx, float v) { C[idx] = (_Float16)v; }

template <typename OutT>
__device__ __forceinline__ void gemm_core(const _Float16* __restrict__ Ab,
                                          const _Float16* __restrict__ Wb,
                                          const float* __restrict__ bias,
                                          OutT* __restrict__ C, int M) {
    int wave = threadIdx.x >> 6;
    int lane = threadIdx.x & 63;
    int col0 = wave * 32;
    int m32 = lane & 31;
    int quad = lane >> 5;

    v8h zeroH = {};

    v8h bf[8];
    const _Float16* wp = Wb + col0 + m32;
#pragma unroll
    for (int kt = 0; kt < 8; kt++) {
        v8h f;
#pragma unroll
        for (int j = 0; j < 8; j++) f[j] = wp[(kt * 16 + quad * 8 + j) * 128];
        bf[kt] = f;
    }
    float bias_v = bias[col0 + m32];

    const int NT = (M + 31) / 32;
    for (int rt = blockIdx.x; rt < NT; rt += gridDim.x) {
        int row0 = rt * 32;
        int grow = row0 + m32;
        bool valid = grow < M;
        const v8h* ap = (const v8h*)(Ab + (size_t)grow * 128 + quad * 8);
        v16f acc;
#pragma unroll
        for (int r = 0; r < 16; r++) acc[r] = 0.0f;
#pragma unroll
        for (int kt = 0; kt < 8; kt++) {
            v8h af = zeroH;
            if (valid) af = ap[kt * 2];
            acc = __builtin_amdgcn_mfma_f32_32x32x16_f16(af, bf[kt], acc, 0, 0, 0);
        }
#pragma unroll
        for (int r = 0; r < 16; r++) {
            int row = (r & 3) + 8 * (r >> 2) + 4 * quad;
            int gr = row0 + row;
            if (gr < M) store_out(C, (size_t)gr * 128 + col0 + m32, acc[r] + bias_v);
        }
    }
}

__global__ __launch_bounds__(256) void gemm_qkv(const _Float16* __restrict__ xh,
                                                const _Float16* __restrict__ Wh,
                                                const float* __restrict__ bq,
                                                const float* __restrict__ bk,
                                                const float* __restrict__ bv,
                                                _Float16* __restrict__ Qh,
                                                _Float16* __restrict__ Kh,
                                                _Float16* __restrict__ Vh) {
    int y = blockIdx.y;
    if (y == 0)      gemm_core(xh, Wh, bq, Qh, N_NODES);
    else if (y == 1) gemm_core(xh, Wh + DIM * DIM, bk, Kh, N_NODES);
    else             gemm_core(xh, Wh + 2 * DIM * DIM, bv, Vh, N_NODES);
}

__global__ __launch_bounds__(256) void gemm_out(const _Float16* __restrict__ Ah,
                                                const _Float16* __restrict__ Wh,
                                                const float* __restrict__ bo,
                                                float* __restrict__ C) {
    gemm_core(Ah, Wh + 3 * DIM * DIM, bo, C, N_NODES);
}

// ---------------- fused attention: f16 gather + 4-stream online softmax ----------------
__global__ __launch_bounds__(256) void fused_attn(const _Float16* __restrict__ Q,
                                                  const _Float16* __restrict__ K,
                                                  const _Float16* __restrict__ V,
                                                  const int* __restrict__ start,
                                                  const int* __restrict__ counts,
                                                  const int* __restrict__ perm,
                                                  const int2* __restrict__ ep,
                                                  _Float16* __restrict__ Aout) {
    int t = blockIdx.x * 256 + threadIdx.x;
    int idx = t >> 3;
    int h = t & 7;
    if (idx >= N_NODES) return;
    int n = perm[idx];

    v8h_u q0, q1;
    q0.v = *(const v8h*)(Q + (size_t)n * 128 + h * 16);
    q1.v = *(const v8h*)(Q + (size_t)n * 128 + h * 16 + 8);

    int s0 = start[n];
    int e1 = s0 + counts[n];

    float m[4] = {-INFINITY, -INFINITY, -INFINITY, -INFINITY};
    float l[4] = {0.0f, 0.0f, 0.0f, 0.0f};
    float acc[4][16];
#pragma unroll
    for (int si = 0; si < 4; si++)
#pragma unroll
        for (int j = 0; j < 16; j++) acc[si][j] = 0.0f;

    auto step = [&](int si, int2 p, v8h_u k0, v8h_u k1, v8h_u v0, v8h_u v1) {
        float ea = __int_as_float(p.y);
        float dot = 0.0f;
#pragma unroll
        for (int j = 0; j < 4; j++) dot = dot2(q0.p[j], k0.p[j], dot);
#pragma unroll
        for (int j = 0; j < 4; j++) dot = dot2(q1.p[j], k1.p[j], dot);
        float s = dot * 0.25f + ea;
        float em = s;
        em = fmaxf(em, __shfl_xor(em, 1));
        em = fmaxf(em, __shfl_xor(em, 2));
        em = fmaxf(em, __shfl_xor(em, 4));
        float nm = fmaxf(m[si], em);
        float scale = __expf(m[si] - nm);
        float ex = __expf(s - nm);
        l[si] = l[si] * scale + ex;
#pragma unroll
        for (int j = 0; j < 8; j++) {
            acc[si][j] = acc[si][j] * scale + ex * (float)v0.e[j];
            acc[si][j + 8] = acc[si][j + 8] * scale + ex * (float)v1.e[j];
        }
        m[si] = nm;
    };

    int i = s0;
    for (; i + 3 < e1; i += 4) {
        int2 p0 = ep[i], p1 = ep[i + 1], p2 = ep[i + 2], p3 = ep[i + 3];
        const v8h* k0p = (const v8h*)(K + (size_t)p0.x * 128 + h * 16);
        const v8h* k1p = (const v8h*)(K + (size_t)p1.x * 128 + h * 16);
        const v8h* k2p = (const v8h*)(K + (size_t)p2.x * 128 + h * 16);
        const v8h* k3p = (const v8h*)(K + (size_t)p3.x * 128 + h * 16);
        const v8h* v0p = (const v8h*)(V + (size_t)p0.x * 128 + h * 16);
        const v8h* v1p = (const v8h*)(V + (size_t)p1.x * 128 + h * 16);
        const v8h* v2p = (const v8h*)(V + (size_t)p2.x * 128 + h * 16);
        const v8h* v3p = (const v8h*)(V + (size_t)p3.x * 128 + h * 16);
        v8h_u K0a, K0b, K1a, K1b, K2a, K2b, K3a, K3b;
        v8h_u V0a, V0b, V1a, V1b, V2a, V2b, V3a, V3b;
        K0a.v = k0p[0]; K0b.v = k0p[1];
        K1a.v = k1p[0]; K1b.v = k1p[1];
        K2a.v = k2p[0]; K2b.v = k2p[1];
        K3a.v = k3p[0]; K3b.v = k3p[1];
        V0a.v = v0p[0]; V0b.v = v0p[1];
        V1a.v = v1p[0]; V1b.v = v1p[1];
        V2a.v = v2p[0]; V2b.v = v2p[1];
        V3a.v = v3p[0]; V3b.v = v3p[1];
        step(0, p0, K0a, K0b, V0a, V0b);
        step(1, p1, K1a, K1b, V1a, V1b);
        step(2, p2, K2a, K2b, V2a, V2b);
        step(3, p3, K3a, K3b, V3a, V3b);
    }
    for (; i < e1; i++) {
        int2 p = ep[i];
        const v8h* kp = (const v8h*)(K + (size_t)p.x * 128 + h * 16);
        const v8h* vp = (const v8h*)(V + (size_t)p.x * 128 + h * 16);
        v8h_u Ka, Kb2, Va, Vb2;
        Ka.v = kp[0]; Kb2.v = kp[1];
        Va.v = vp[0]; Vb2.v = vp[1];
        step(0, p, Ka, Kb2, Va, Vb2);
    }

    // merge 4 streams
    float mm = fmaxf(fmaxf(m[0], m[1]), fmaxf(m[2], m[3]));
    float w[4], ltot = 0.0f;
#pragma unroll
    for (int si = 0; si < 4; si++) {
        w[si] = (l[si] > 0.0f) ? __expf(m[si] - mm) : 0.0f;
        ltot += l[si] * w[si];
    }
    float inv = 1.0f / (ltot + 1e-8f);

    _Float16 tmp[16];
#pragma unroll
    for (int j = 0; j < 16; j++) {
        float o = (acc[0][j] * w[0] + acc[1][j] * w[1] + acc[2][j] * w[2] + acc[3][j] * w[3]) * inv;
        tmp[j] = (_Float16)o;
    }
    _Float16* o = Aout + (size_t)n * 128 + h * 16;
    *(v8h*)(o) = *(v8h*)tmp;
    *(v8h*)(o + 8) = *(v8h*)(tmp + 8);
}

extern "C" void kernel_launch(void* const* d_in, const int* in_sizes, int n_in,
                              void* d_out, int out_size, void* d_ws, size_t ws_size,
                              hipStream_t stream) {
    const float* x = (const float*)d_in[0];
    const int* ei = (const int*)d_in[1];
    const float* eattr = (const float*)d_in[2];
    const float* Wq = (const float*)d_in[3];
    const float* bq = (const float*)d_in[4];
    const float* Wk = (const float*)d_in[5];
    const float* bk = (const float*)d_in[6];
    const float* Wv = (const float*)d_in[7];
    const float* bv = (const float*)d_in[8];
    const float* Wo = (const float*)d_in[9];
    const float* bo = (const float*)d_in[10];
    float* out = (float*)d_out;

    const int* rowi = ei;
    const int* coli = ei + N_EDGES;

    // workspace carve
    _Float16* Qh = (_Float16*)d_ws;
    _Float16* Kh = Qh + (size_t)N_NODES * DIM;
    _Float16* Vh = Kh + (size_t)N_NODES * DIM;
    _Float16* xh = Vh + (size_t)N_NODES * DIM;
    _Float16* Ah = xh + (size_t)N_NODES * DIM;
    _Float16* Wh = Ah + (size_t)N_NODES * DIM;
    int* counts = (int*)(Wh + 4 * DIM * DIM);
    int* start = counts + N_NODES;
    int* writeptr = start + N_NODES;
    int* partials = writeptr + N_NODES;
    int* offsets = partials + 256;
    int* bins = offsets + 256;
    int* bptr = bins + 64;
    int* perm = bptr + 64;
    int2* ep = (int2*)(perm + N_NODES);

    int eblocks = (N_EDGES + 255) / 256;
    int pblocks = (N_NODES * DIM / 4 + 255) / 256;

    // prep: zero counts/bins + f16 conversions
    prep_kernel<<<pblocks, 256, 0, stream>>>(x, Wq, Wk, Wv, Wo, xh, Wh, counts, bins);
    // CSR build + degree-balanced permutation
    hist_kernel<<<eblocks, 256, 0, stream>>>(rowi, counts);
    reduce_partials<<<NBLK, 256, 0, stream>>>(counts, partials);
    scan_partials<<<1, 256, 0, stream>>>(partials, offsets);
    block_scan<<<NBLK, 256, 0, stream>>>(counts, offsets, start, writeptr, bins);
    scatter_kernel<<<eblocks, 256, 0, stream>>>(rowi, coli, eattr, writeptr, ep);
    deg_scan<<<1, 64, 0, stream>>>(bins, bptr);
    deg_scatter<<<NBLK, 256, 0, stream>>>(counts, bptr, perm);

    // Q/K/V projections (f16 MFMA)
    gemm_qkv<<<dim3(392, 3), 256, 0, stream>>>(xh, Wh, bq, bk, bv, Qh, Kh, Vh);

    // fused gather-attention
    int ablocks = (N_NODES * HEADS + 255) / 256;
    fused_attn<<<ablocks, 256, 0, stream>>>(Qh, Kh, Vh, start, counts, perm, ep, Ah);

    // output projection
    gemm_out<<<392, 256, 0, stream>>>(Ah, Wh, bo, out);
}

// Round 7
// 251.846 us; speedup vs baseline: 1.7247x; 1.0555x over previous
//
#include <hip/hip_runtime.h>
#include <math.h>

#define N_NODES 50000
#define N_EDGES 600000
#define DIM 128
#define HEADS 8
#define NBLK 196
#define DBINS 64
#define EBLK 2344  // (N_EDGES+255)/256

typedef _Float16 v8h __attribute__((ext_vector_type(8)));
typedef _Float16 v2h __attribute__((ext_vector_type(2)));
typedef float v16f __attribute__((ext_vector_type(16)));

union v8h_u {
    v8h v;
    v2h p[4];
    _Float16 e[8];
};

__device__ __forceinline__ float dot2(v2h a, v2h b, float c) {
#if __has_builtin(__builtin_amdgcn_fdot2)
    return __builtin_amdgcn_fdot2(a, b, c, false);
#else
    return c + (float)a[0] * (float)b[0] + (float)a[1] * (float)b[1];
#endif
}

// ---------------- fused prep: zero counts/bins + convert x to f16 + W to MFMA-frag layout ----------------
// Wfrag flat layout (per matrix 16384 shorts): idx = wave*4096 + kt*512 + lane*8 + j
//   value = W[k][n], k = kt*16 + (lane>>5)*8 + j, n = wave*32 + (lane&31)
__global__ __launch_bounds__(256) void prep_kernel(const float* __restrict__ x,
                                                   const float* __restrict__ Wq,
                                                   const float* __restrict__ Wk,
                                                   const float* __restrict__ Wv,
                                                   const float* __restrict__ Wo,
                                                   _Float16* __restrict__ xh,
                                                   _Float16* __restrict__ Wfrag,
                                                   int* __restrict__ counts,
                                                   int* __restrict__ bins) {
    int i = blockIdx.x * 256 + threadIdx.x;
    if (i < N_NODES) counts[i] = 0;
    if (i < DBINS) bins[i] = 0;
    int base = i * 4;
    if (base < N_NODES * DIM) {
        float4 v = *(const float4*)(x + base);
        _Float16 o[4] = {(_Float16)v.x, (_Float16)v.y, (_Float16)v.z, (_Float16)v.w};
        *(short4*)(xh + base) = *(short4*)o;
    }
    if (i < 16384) {
        int mat = i >> 12;
        int rem = i & 4095;
        int wave = rem >> 10;
        int kt = (rem >> 7) & 7;
        int lane = (rem >> 1) & 63;
        int jh = (rem & 1) * 4;
        const float* src = (mat == 0) ? Wq : (mat == 1) ? Wk : (mat == 2) ? Wv : Wo;
        int n = wave * 32 + (lane & 31);
        int kbase = kt * 16 + (lane >> 5) * 8 + jh;
        _Float16 o[4];
#pragma unroll
        for (int j = 0; j < 4; j++) o[j] = (_Float16)src[(kbase + j) * 128 + n];
        *(short4*)(Wfrag + base) = *(short4*)o;
    }
}

// ---------------- CSR build ----------------
__global__ __launch_bounds__(256) void hist_kernel(const int* __restrict__ rowi,
                                                   int* __restrict__ counts) {
    int e = blockIdx.x * 256 + threadIdx.x;
    if (e >= N_EDGES) return;
    atomicAdd(counts + rowi[e], 1);
}

__global__ __launch_bounds__(256) void reduce_partials(const int* __restrict__ counts,
                                                       int* __restrict__ partials) {
    int idx = blockIdx.x * 256 + threadIdx.x;
    int v = (idx < N_NODES) ? counts[idx] : 0;
#pragma unroll
    for (int off = 32; off > 0; off >>= 1) v += __shfl_down(v, off);
    __shared__ int ws4[4];
    if ((threadIdx.x & 63) == 0) ws4[threadIdx.x >> 6] = v;
    __syncthreads();
    if (threadIdx.x == 0) partials[blockIdx.x] = ws4[0] + ws4[1] + ws4[2] + ws4[3];
}

__global__ __launch_bounds__(256) void scan_partials(const int* __restrict__ partials,
                                                     int* __restrict__ offsets) {
    __shared__ int sh[256];
    int t = threadIdx.x;
    int v = (t < NBLK) ? partials[t] : 0;
    sh[t] = v;
    __syncthreads();
    for (int off = 1; off < 256; off <<= 1) {
        int a = sh[t];
        int b = (t >= off) ? sh[t - off] : 0;
        __syncthreads();
        sh[t] = a + b;
        __syncthreads();
    }
    if (t < NBLK) offsets[t] = sh[t] - v;  // exclusive
}

// block-level scan for CSR starts + fused degree histogram
__global__ __launch_bounds__(256) void block_scan(const int* __restrict__ counts,
                                                  const int* __restrict__ offsets,
                                                  int* __restrict__ start,
                                                  int* __restrict__ writeptr,
                                                  int* __restrict__ bins) {
    __shared__ int sh[256];
    __shared__ int lb[DBINS];
    int t = threadIdx.x;
    int idx = blockIdx.x * 256 + t;
    int v = (idx < N_NODES) ? counts[idx] : 0;
    if (t < DBINS) lb[t] = 0;
    sh[t] = v;
    __syncthreads();
    for (int off = 1; off < 256; off <<= 1) {
        int a = sh[t];
        int b = (t >= off) ? sh[t - off] : 0;
        __syncthreads();
        sh[t] = a + b;
        __syncthreads();
    }
    if (idx < N_NODES) {
        int s = offsets[blockIdx.x] + sh[t] - v;
        start[idx] = s;
        writeptr[idx] = s;
        atomicAdd(lb + min(v, DBINS - 1), 1);
    }
    __syncthreads();
    if (t < DBINS) {
        int c = lb[t];
        if (c) atomicAdd(bins + t, c);
    }
}

// DESCENDING degree order: bin 63 first (longest waves dispatch earliest)
__global__ __launch_bounds__(64) void deg_scan(const int* __restrict__ bins,
                                               int* __restrict__ bptr) {
    int t = threadIdx.x;
    int v = bins[t];
    int s = v;
#pragma unroll
    for (int off = 1; off < 64; off <<= 1) {
        int u = __shfl_up(s, off);
        if (t >= off) s += u;
    }
    int total = __shfl(s, 63);
    bptr[t] = total - s;  // sum of bins strictly greater than t
}

// merged scatter: blocks [0,NBLK) do degree counting-sort scatter; rest do edge scatter
__global__ __launch_bounds__(256) void scatter_all(const int* __restrict__ counts,
                                                   int* __restrict__ bptr,
                                                   int* __restrict__ perm,
                                                   const int* __restrict__ rowi,
                                                   const int* __restrict__ coli,
                                                   const float* __restrict__ eattr,
                                                   int* __restrict__ writeptr,
                                                   int2* __restrict__ ep) {
    if (blockIdx.x < NBLK) {
        __shared__ int lhist[DBINS];
        __shared__ int lbase[DBINS];
        if (threadIdx.x < DBINS) lhist[threadIdx.x] = 0;
        __syncthreads();
        int i = blockIdx.x * 256 + threadIdx.x;
        int b = -1, r = 0;
        if (i < N_NODES) {
            b = min(counts[i], DBINS - 1);
            r = atomicAdd(lhist + b, 1);
        }
        __syncthreads();
        if (threadIdx.x < DBINS) {
            int c = lhist[threadIdx.x];
            lbase[threadIdx.x] = c ? atomicAdd(bptr + threadIdx.x, c) : 0;
        }
        __syncthreads();
        if (b >= 0) perm[lbase[b] + r] = i;
    } else {
        int e = (blockIdx.x - NBLK) * 256 + threadIdx.x;
        if (e >= N_EDGES) return;
        int r = rowi[e];
        int pos = atomicAdd(writeptr + r, 1);
        ep[pos] = make_int2(coli[e], __float_as_int(eattr[e]));
    }
}

// ---------------- f16 MFMA GEMM core (frag-layout W) ----------------
__device__ __forceinline__ void store_out(float* C, size_t idx, float v) { C[idx] = v; }
__device__ __forceinline__ void store_out(_Float16* C, size_t idx, float v) { C[idx] = (_Float16)v; }

template <typename OutT>
__device__ __forceinline__ void gemm_core(const _Float16* __restrict__ Ab,
                                          const _Float16* __restrict__ Wfrag_mat,
                                          const float* __restrict__ bias,
                                          OutT* __restrict__ C, int M) {
    int wave = threadIdx.x >> 6;
    int lane = threadIdx.x & 63;
    int col0 = wave * 32;
    int m32 = lane & 31;
    int quad = lane >> 5;

    v8h zeroH = {};

    v8h bf[8];
#pragma unroll
    for (int kt = 0; kt < 8; kt++)
        bf[kt] = *(const v8h*)(Wfrag_mat + wave * 4096 + kt * 512 + lane * 8);
    float bias_v = bias[col0 + m32];

    const int NT = (M + 31) / 32;
    for (int rt = blockIdx.x; rt < NT; rt += gridDim.x) {
        int row0 = rt * 32;
        int grow = row0 + m32;
        bool valid = grow < M;
        const v8h* ap = (const v8h*)(Ab + (size_t)grow * 128 + quad * 8);
        v16f acc;
#pragma unroll
        for (int r = 0; r < 16; r++) acc[r] = 0.0f;
#pragma unroll
        for (int kt = 0; kt < 8; kt++) {
            v8h af = zeroH;
            if (valid) af = ap[kt * 2];
            acc = __builtin_amdgcn_mfma_f32_32x32x16_f16(af, bf[kt], acc, 0, 0, 0);
        }
#pragma unroll
        for (int r = 0; r < 16; r++) {
            int row = (r & 3) + 8 * (r >> 2) + 4 * quad;
            int gr = row0 + row;
            if (gr < M) store_out(C, (size_t)gr * 128 + col0 + m32, acc[r] + bias_v);
        }
    }
}

__global__ __launch_bounds__(256) void gemm_qkv(const _Float16* __restrict__ xh,
                                                const _Float16* __restrict__ Wfrag,
                                                const float* __restrict__ bq,
                                                const float* __restrict__ bk,
                                                const float* __restrict__ bv,
                                                _Float16* __restrict__ Qh,
                                                _Float16* __restrict__ Kh,
                                                _Float16* __restrict__ Vh) {
    int y = blockIdx.y;
    if (y == 0)      gemm_core(xh, Wfrag, bq, Qh, N_NODES);
    else if (y == 1) gemm_core(xh, Wfrag + 16384, bk, Kh, N_NODES);
    else             gemm_core(xh, Wfrag + 2 * 16384, bv, Vh, N_NODES);
}

__global__ __launch_bounds__(256) void gemm_out(const _Float16* __restrict__ Ah,
                                                const _Float16* __restrict__ Wfrag,
                                                const float* __restrict__ bo,
                                                float* __restrict__ C) {
    gemm_core(Ah, Wfrag + 3 * 16384, bo, C, N_NODES);
}

// ---------------- fused attention: f16 gather + 4-stream online softmax ----------------
__global__ __launch_bounds__(256) void fused_attn(const _Float16* __restrict__ Q,
                                                  const _Float16* __restrict__ K,
                                                  const _Float16* __restrict__ V,
                                                  const int* __restrict__ start,
                                                  const int* __restrict__ counts,
                                                  const int* __restrict__ perm,
                                                  const int2* __restrict__ ep,
                                                  _Float16* __restrict__ Aout) {
    int t = blockIdx.x * 256 + threadIdx.x;
    int idx = t >> 3;
    int h = t & 7;
    if (idx >= N_NODES) return;
    int n = perm[idx];

    v8h_u q0, q1;
    q0.v = *(const v8h*)(Q + (size_t)n * 128 + h * 16);
    q1.v = *(const v8h*)(Q + (size_t)n * 128 + h * 16 + 8);

    int s0 = start[n];
    int e1 = s0 + counts[n];

    float m[4] = {-INFINITY, -INFINITY, -INFINITY, -INFINITY};
    float l[4] = {0.0f, 0.0f, 0.0f, 0.0f};
    float acc[4][16];
#pragma unroll
    for (int si = 0; si < 4; si++)
#pragma unroll
        for (int j = 0; j < 16; j++) acc[si][j] = 0.0f;

    auto step = [&](int si, int2 p, v8h_u k0, v8h_u k1, v8h_u v0, v8h_u v1) {
        float ea = __int_as_float(p.y);
        float dot = 0.0f;
#pragma unroll
        for (int j = 0; j < 4; j++) dot = dot2(q0.p[j], k0.p[j], dot);
#pragma unroll
        for (int j = 0; j < 4; j++) dot = dot2(q1.p[j], k1.p[j], dot);
        float s = dot * 0.25f + ea;
        float em = s;
        em = fmaxf(em, __shfl_xor(em, 1));
        em = fmaxf(em, __shfl_xor(em, 2));
        em = fmaxf(em, __shfl_xor(em, 4));
        float nm = fmaxf(m[si], em);
        float scale = __expf(m[si] - nm);
        float ex = __expf(s - nm);
        l[si] = l[si] * scale + ex;
#pragma unroll
        for (int j = 0; j < 8; j++) {
            acc[si][j] = acc[si][j] * scale + ex * (float)v0.e[j];
            acc[si][j + 8] = acc[si][j + 8] * scale + ex * (float)v1.e[j];
        }
        m[si] = nm;
    };

    int i = s0;
    for (; i + 3 < e1; i += 4) {
        int2 p0 = ep[i], p1 = ep[i + 1], p2 = ep[i + 2], p3 = ep[i + 3];
        const v8h* k0p = (const v8h*)(K + (size_t)p0.x * 128 + h * 16);
        const v8h* k1p = (const v8h*)(K + (size_t)p1.x * 128 + h * 16);
        const v8h* k2p = (const v8h*)(K + (size_t)p2.x * 128 + h * 16);
        const v8h* k3p = (const v8h*)(K + (size_t)p3.x * 128 + h * 16);
        const v8h* v0p = (const v8h*)(V + (size_t)p0.x * 128 + h * 16);
        const v8h* v1p = (const v8h*)(V + (size_t)p1.x * 128 + h * 16);
        const v8h* v2p = (const v8h*)(V + (size_t)p2.x * 128 + h * 16);
        const v8h* v3p = (const v8h*)(V + (size_t)p3.x * 128 + h * 16);
        v8h_u K0a, K0b, K1a, K1b, K2a, K2b, K3a, K3b;
        v8h_u V0a, V0b, V1a, V1b, V2a, V2b, V3a, V3b;
        K0a.v = k0p[0]; K0b.v = k0p[1];
        K1a.v = k1p[0]; K1b.v = k1p[1];
        K2a.v = k2p[0]; K2b.v = k2p[1];
        K3a.v = k3p[0]; K3b.v = k3p[1];
        V0a.v = v0p[0]; V0b.v = v0p[1];
        V1a.v = v1p[0]; V1b.v = v1p[1];
        V2a.v = v2p[0]; V2b.v = v2p[1];
        V3a.v = v3p[0]; V3b.v = v3p[1];
        step(0, p0, K0a, K0b, V0a, V0b);
        step(1, p1, K1a, K1b, V1a, V1b);
        step(2, p2, K2a, K2b, V2a, V2b);
        step(3, p3, K3a, K3b, V3a, V3b);
    }
    for (; i < e1; i++) {
        int2 p = ep[i];
        const v8h* kp = (const v8h*)(K + (size_t)p.x * 128 + h * 16);
        const v8h* vp = (const v8h*)(V + (size_t)p.x * 128 + h * 16);
        v8h_u Ka, Kb2, Va, Vb2;
        Ka.v = kp[0]; Kb2.v = kp[1];
        Va.v = vp[0]; Vb2.v = vp[1];
        step(0, p, Ka, Kb2, Va, Vb2);
    }

    // merge 4 streams
    float mm = fmaxf(fmaxf(m[0], m[1]), fmaxf(m[2], m[3]));
    float w[4], ltot = 0.0f;
#pragma unroll
    for (int si = 0; si < 4; si++) {
        w[si] = (l[si] > 0.0f) ? __expf(m[si] - mm) : 0.0f;
        ltot += l[si] * w[si];
    }
    float inv = 1.0f / (ltot + 1e-8f);

    _Float16 tmp[16];
#pragma unroll
    for (int j = 0; j < 16; j++) {
        float o = (acc[0][j] * w[0] + acc[1][j] * w[1] + acc[2][j] * w[2] + acc[3][j] * w[3]) * inv;
        tmp[j] = (_Float16)o;
    }
    _Float16* o = Aout + (size_t)n * 128 + h * 16;
    *(v8h*)(o) = *(v8h*)tmp;
    *(v8h*)(o + 8) = *(v8h*)(tmp + 8);
}

extern "C" void kernel_launch(void* const* d_in, const int* in_sizes, int n_in,
                              void* d_out, int out_size, void* d_ws, size_t ws_size,
                              hipStream_t stream) {
    const float* x = (const float*)d_in[0];
    const int* ei = (const int*)d_in[1];
    const float* eattr = (const float*)d_in[2];
    const float* Wq = (const float*)d_in[3];
    const float* bq = (const float*)d_in[4];
    const float* Wk = (const float*)d_in[5];
    const float* bk = (const float*)d_in[6];
    const float* Wv = (const float*)d_in[7];
    const float* bv = (const float*)d_in[8];
    const float* Wo = (const float*)d_in[9];
    const float* bo = (const float*)d_in[10];
    float* out = (float*)d_out;

    const int* rowi = ei;
    const int* coli = ei + N_EDGES;

    // workspace carve
    _Float16* Qh = (_Float16*)d_ws;
    _Float16* Kh = Qh + (size_t)N_NODES * DIM;
    _Float16* Vh = Kh + (size_t)N_NODES * DIM;
    _Float16* xh = Vh + (size_t)N_NODES * DIM;
    _Float16* Ah = xh + (size_t)N_NODES * DIM;
    _Float16* Wfrag = Ah + (size_t)N_NODES * DIM;  // 4*16384 shorts
    int* counts = (int*)(Wfrag + 4 * 16384);
    int* start = counts + N_NODES;
    int* writeptr = start + N_NODES;
    int* partials = writeptr + N_NODES;
    int* offsets = partials + 256;
    int* bins = offsets + 256;
    int* bptr = bins + 64;
    int* perm = bptr + 64;
    int2* ep = (int2*)(perm + N_NODES);

    int pblocks = (N_NODES * DIM / 4 + 255) / 256;

    // prep: zero counts/bins + f16 conversions + W frag layout
    prep_kernel<<<pblocks, 256, 0, stream>>>(x, Wq, Wk, Wv, Wo, xh, Wfrag, counts, bins);
    // CSR build + degree permutation (descending)
    hist_kernel<<<EBLK, 256, 0, stream>>>(rowi, counts);
    reduce_partials<<<NBLK, 256, 0, stream>>>(counts, partials);
    scan_partials<<<1, 256, 0, stream>>>(partials, offsets);
    block_scan<<<NBLK, 256, 0, stream>>>(counts, offsets, start, writeptr, bins);
    deg_scan<<<1, 64, 0, stream>>>(bins, bptr);
    scatter_all<<<NBLK + EBLK, 256, 0, stream>>>(counts, bptr, perm, rowi, coli, eattr,
                                                 writeptr, ep);

    // Q/K/V projections (f16 MFMA)
    gemm_qkv<<<dim3(392, 3), 256, 0, stream>>>(xh, Wfrag, bq, bk, bv, Qh, Kh, Vh);

    // fused gather-attention
    int ablocks = (N_NODES * HEADS + 255) / 256;
    fused_attn<<<ablocks, 256, 0, stream>>>(Qh, Kh, Vh, start, counts, perm, ep, Ah);

    // output projection
    gemm_out<<<392, 256, 0, stream>>>(Ah, Wfrag, bo, out);
}